// Round 1
// baseline (139.488 us; speedup 1.0000x reference)
//
#include <hip/hip_runtime.h>
#include <math.h>

#define HH 256
#define WW 256
#define NG 714
#define FOCALF 128.0f
#define EPS2D_F 0.3f
#define ALPHA_MIN_F (1.0f/255.0f)
#define ALPHA_MAX_F 0.999f
#define CAM_T_F 8.0f
#define PG 9   // floats per gaussian in sorted param array: mx,my,halfA,B,halfC,opac,r,g,b

// Kernel 1: per-gaussian projection + conic + stable depth sort (counting ranks).
__global__ __launch_bounds__(1024) void gs_preprocess_sort(
    const float* __restrict__ means, const float* __restrict__ quats,
    const float* __restrict__ scales, const float* __restrict__ opacities,
    const float* __restrict__ rgbs, float* __restrict__ params)
{
    __shared__ float s_tz[NG];
    const int i = threadIdx.x;
    float mx=0.f,my=0.f,hA=0.f,Bc=0.f,hC=0.f,op=0.f,cr=0.f,cg=0.f,cb=0.f,tz=0.f;
    if (i < NG) {
        float m0 = means[i*3+0], m1 = means[i*3+1], m2 = means[i*3+2];
        float qw = quats[i*4+0], qx = quats[i*4+1], qy = quats[i*4+2], qz = quats[i*4+3];
        float qn = rsqrtf(qw*qw + qx*qx + qy*qy + qz*qz);
        qw*=qn; qx*=qn; qy*=qn; qz*=qn;
        float sx = scales[i*3+0], sy = scales[i*3+1], sz = scales[i*3+2];
        float s0 = sx*sx, s1 = sy*sy, s2 = sz*sz;
        // quat -> rotmat (reference layout: q = [w,x,y,z])
        float R00 = 1.f-2.f*(qy*qy+qz*qz), R01 = 2.f*(qx*qy-qw*qz), R02 = 2.f*(qx*qz+qw*qy);
        float R10 = 2.f*(qx*qy+qw*qz),     R11 = 1.f-2.f*(qx*qx+qz*qz), R12 = 2.f*(qy*qz-qw*qx);
        float R20 = 2.f*(qx*qz-qw*qy),     R21 = 2.f*(qy*qz+qw*qx),     R22 = 1.f-2.f*(qx*qx+qy*qy);
        // cov3d = R diag(s^2) R^T  (symmetric, 6 entries)
        float S00 = R00*R00*s0 + R01*R01*s1 + R02*R02*s2;
        float S01 = R00*R10*s0 + R01*R11*s1 + R02*R12*s2;
        float S02 = R00*R20*s0 + R01*R21*s1 + R02*R22*s2;
        float S11 = R10*R10*s0 + R11*R11*s1 + R12*R12*s2;
        float S12 = R10*R20*s0 + R11*R21*s1 + R12*R22*s2;
        float S22 = R20*R20*s0 + R21*R21*s1 + R22*R22*s2;
        float tx = m0, ty = m1; tz = m2 + CAM_T_F;
        float inv = 1.f/tz;
        mx = FOCALF*tx*inv + 0.5f*WW;
        my = FOCALF*ty*inv + 0.5f*HH;
        // J rows: (j0, 0, j2), (0, j0, j5)
        float j0 = FOCALF*inv;
        float j2 = -FOCALF*tx*inv*inv;
        float j5 = -FOCALF*ty*inv*inv;
        float a = j0*j0*S00 + 2.f*j0*j2*S02 + j2*j2*S22 + EPS2D_F;
        float b = j0*(j0*S01 + j2*S12) + j5*(j0*S02 + j2*S22);
        float c = j0*j0*S11 + 2.f*j0*j5*S12 + j5*j5*S22 + EPS2D_F;
        float det = a*c - b*b;
        float idet = 1.f/det;
        hA = 0.5f*c*idet;           // 0.5*conicA
        Bc = -b*idet;               // conicB
        hC = 0.5f*a*idet;           // 0.5*conicC
        op = 1.f/(1.f+__expf(-opacities[i]));
        cr = 1.f/(1.f+__expf(-rgbs[i*3+0]));
        cg = 1.f/(1.f+__expf(-rgbs[i*3+1]));
        cb = 1.f/(1.f+__expf(-rgbs[i*3+2]));
        s_tz[i] = tz;
    }
    __syncthreads();
    if (i < NG) {
        // stable rank == position under jnp.argsort(tz) (ascending, stable)
        int rank = 0;
        for (int j = 0; j < NG; ++j) {
            float tj = s_tz[j];
            rank += (tj < tz) || (tj == tz && j < i);
        }
        float* p = params + rank*PG;
        p[0]=mx; p[1]=my; p[2]=hA; p[3]=Bc; p[4]=hC; p[5]=op; p[6]=cr; p[7]=cg; p[8]=cb;
    }
}

// Kernel 2: per-pixel front-to-back compositing over all sorted gaussians.
__global__ __launch_bounds__(256) void gs_composite(
    const float* __restrict__ params, float* __restrict__ out)
{
    __shared__ float sp[NG*PG];
    for (int k = threadIdx.x; k < NG*PG; k += 256) sp[k] = params[k];
    __syncthreads();

    const int pix = blockIdx.x*256 + threadIdx.x;
    const float px = (float)(pix & (WW-1)) + 0.5f;
    const float py = (float)(pix >> 8) + 0.5f;

    float T = 1.f, r = 0.f, g = 0.f, bl = 0.f;
    const float* p = sp;
    #pragma unroll 2
    for (int n = 0; n < NG; ++n, p += PG) {
        float dx = px - p[0];
        float dy = py - p[1];
        // sigma = 0.5*A*dx^2 + B*dx*dy + 0.5*C*dy^2  (halfA/halfC prefolded)
        float sigma = p[2]*dx*dx + p[3]*dx*dy + p[4]*dy*dy;
        float alpha = p[5]*__expf(-sigma);
        alpha = fminf(alpha, ALPHA_MAX_F);
        alpha = (alpha < ALPHA_MIN_F) ? 0.f : alpha;
        float w = T * alpha;
        r  += w*p[6];
        g  += w*p[7];
        bl += w*p[8];
        T  -= w;              // T *= (1 - alpha)
    }
    out[pix*3+0] = r;
    out[pix*3+1] = g;
    out[pix*3+2] = bl;
}

extern "C" void kernel_launch(void* const* d_in, const int* in_sizes, int n_in,
                              void* d_out, int out_size, void* d_ws, size_t ws_size,
                              hipStream_t stream) {
    // d_in: 0=coords (unused by reference), 1=means, 2=quats, 3=scales, 4=opacities, 5=rgbs
    const float* means = (const float*)d_in[1];
    const float* quats = (const float*)d_in[2];
    const float* scales = (const float*)d_in[3];
    const float* opac  = (const float*)d_in[4];
    const float* rgbs  = (const float*)d_in[5];
    float* params = (float*)d_ws;   // NG*PG floats

    gs_preprocess_sort<<<1, 1024, 0, stream>>>(means, quats, scales, opac, rgbs, params);
    gs_composite<<<(HH*WW)/256, 256, 0, stream>>>(params, (float*)d_out);
}

// Round 2
// 126.671 us; speedup vs baseline: 1.1012x; 1.1012x over previous
//
#include <hip/hip_runtime.h>
#include <math.h>

#define HH 256
#define WW 256
#define NG 714
#define NGP 716            // padded to multiple of 4 for float4 rank loop
#define FOCALF 128.0f
#define EPS2D_F 0.3f
#define ALPHA_MIN_F (1.0f/255.0f)
#define ALPHA_MAX_F 0.999f
#define CAM_T_F 8.0f
#define PG 12              // floats per sorted gaussian row (48 B, 16B-aligned)
#define SEGSZ 179          // gaussians per depth segment (4 segs: 179,179,179,177)

// Kernel 1: projection + conic + stable depth rank + scatter into sorted rows.
// 12 blocks x 64 threads; each block redundantly stages all tz into LDS
// (cheap: 714 loads, L2-hit after block 0), rank loop is float4 LDS broadcast.
__global__ __launch_bounds__(64) void gs_prep(
    const float* __restrict__ means, const float* __restrict__ quats,
    const float* __restrict__ scales, const float* __restrict__ opacities,
    const float* __restrict__ rgbs, float* __restrict__ params)
{
    __shared__ float s_tz[NGP];
    const int lane = threadIdx.x;
    const int i = blockIdx.x * 64 + lane;

    for (int j = lane; j < NGP; j += 64)
        s_tz[j] = (j < NG) ? (means[3*j+2] + CAM_T_F) : INFINITY;
    __syncthreads();

    if (i >= NG) return;

    float m0 = means[i*3+0], m1 = means[i*3+1];
    float tz = s_tz[i];
    float qw = quats[i*4+0], qx = quats[i*4+1], qy = quats[i*4+2], qz = quats[i*4+3];
    float qn = rsqrtf(qw*qw + qx*qx + qy*qy + qz*qz);
    qw*=qn; qx*=qn; qy*=qn; qz*=qn;
    float sx = scales[i*3+0], sy = scales[i*3+1], sz = scales[i*3+2];
    float s0 = sx*sx, s1 = sy*sy, s2 = sz*sz;
    float R00 = 1.f-2.f*(qy*qy+qz*qz), R01 = 2.f*(qx*qy-qw*qz), R02 = 2.f*(qx*qz+qw*qy);
    float R10 = 2.f*(qx*qy+qw*qz),     R11 = 1.f-2.f*(qx*qx+qz*qz), R12 = 2.f*(qy*qz-qw*qx);
    float R20 = 2.f*(qx*qz-qw*qy),     R21 = 2.f*(qy*qz+qw*qx),     R22 = 1.f-2.f*(qx*qx+qy*qy);
    float S00 = R00*R00*s0 + R01*R01*s1 + R02*R02*s2;
    float S01 = R00*R10*s0 + R01*R11*s1 + R02*R12*s2;
    float S02 = R00*R20*s0 + R01*R21*s1 + R02*R22*s2;
    float S11 = R10*R10*s0 + R11*R11*s1 + R12*R12*s2;
    float S12 = R10*R20*s0 + R11*R21*s1 + R12*R22*s2;
    float S22 = R20*R20*s0 + R21*R21*s1 + R22*R22*s2;
    float inv = 1.f/tz;
    float mx = FOCALF*m0*inv + 0.5f*WW;
    float my = FOCALF*m1*inv + 0.5f*HH;
    float j0 = FOCALF*inv;
    float j2 = -FOCALF*m0*inv*inv;
    float j5 = -FOCALF*m1*inv*inv;
    float a = j0*j0*S00 + 2.f*j0*j2*S02 + j2*j2*S22 + EPS2D_F;
    float b = j0*(j0*S01 + j2*S12) + j5*(j0*S02 + j2*S22);
    float c = j0*j0*S11 + 2.f*j0*j5*S12 + j5*j5*S22 + EPS2D_F;
    float det = a*c - b*b;
    float idet = 1.f/det;
    float hA = 0.5f*c*idet;     // 0.5*conicA
    float Bc = -b*idet;         // conicB
    float hC = 0.5f*a*idet;     // 0.5*conicC
    float op = 1.f/(1.f+__expf(-opacities[i]));
    float cr = 1.f/(1.f+__expf(-rgbs[i*3+0]));
    float cg = 1.f/(1.f+__expf(-rgbs[i*3+1]));
    float cb = 1.f/(1.f+__expf(-rgbs[i*3+2]));

    // stable ascending rank over tz (== jnp.argsort position), float4 LDS broadcast
    const float4* t4 = (const float4*)s_tz;
    int rank = 0;
    #pragma unroll 4
    for (int jj = 0; jj < NGP/4; ++jj) {
        float4 v = t4[jj];
        int j = 4*jj;
        rank += (v.x < tz) || (v.x == tz && (j+0) < i);
        rank += (v.y < tz) || (v.y == tz && (j+1) < i);
        rank += (v.z < tz) || (v.z == tz && (j+2) < i);
        rank += (v.w < tz) || (v.w == tz && (j+3) < i);
    }

    float4* row = (float4*)(params + rank*PG);
    row[0] = make_float4(mx, my, hA, Bc);
    row[1] = make_float4(hC, op, cr, cg);
    row[2] = make_float4(cb, 0.f, 0.f, 0.f);
}

// Kernel 2: per-pixel front-to-back compositing, 4 depth segments per block.
// Gaussian params read from GLOBAL with wave-uniform addresses -> scalar
// (s_load) path through the scalar cache: zero LDS traffic in the hot loop.
__global__ __launch_bounds__(1024) void gs_composite(
    const float* __restrict__ params, float* __restrict__ out)
{
    __shared__ float4 part[4][256];
    const int tid = threadIdx.x;
    // threadIdx.y is wave-constant (blockDim.x=256); readfirstlane makes it
    // an SGPR so the loop bounds -> loop counter -> load addresses are
    // provably uniform and eligible for SMEM scalarization.
    const int seg = __builtin_amdgcn_readfirstlane((int)threadIdx.y);
    const int pix = blockIdx.x*256 + tid;
    const float px = (float)(pix & (WW-1)) + 0.5f;
    const float py = (float)(pix >> 8) + 0.5f;
    const int n0 = seg * SEGSZ;
    const int n1 = (n0 + SEGSZ < NG) ? (n0 + SEGSZ) : NG;

    const float4* __restrict__ p4 = (const float4*)params;
    float T = 1.f, r = 0.f, g = 0.f, b = 0.f;
    #pragma unroll 4
    for (int n = n0; n < n1; ++n) {
        float4 r0 = p4[3*n+0];          // mx,my,hA,B
        float4 r1 = p4[3*n+1];          // hC,op,cr,cg
        float cb = params[PG*n+8];      // cb
        float dx = px - r0.x;
        float dy = py - r0.y;
        float sigma = r0.z*dx*dx + r0.w*dx*dy + r1.x*dy*dy;
        float alpha = r1.y*__expf(-sigma);
        alpha = fminf(alpha, ALPHA_MAX_F);
        alpha = (alpha < ALPHA_MIN_F) ? 0.f : alpha;
        float w = T * alpha;
        r += w*r1.z; g += w*r1.w; b += w*cb;
        T -= w;
    }
    part[seg][tid] = make_float4(r, g, b, T);
    __syncthreads();

    if (threadIdx.y == 0) {
        float4 p0 = part[0][tid], p1 = part[1][tid], p2 = part[2][tid], p3 = part[3][tid];
        // C = C0 + T0*(C1 + T1*(C2 + T2*C3))
        float R = p0.x + p0.w*(p1.x + p1.w*(p2.x + p2.w*p3.x));
        float G = p0.y + p0.w*(p1.y + p1.w*(p2.y + p2.w*p3.y));
        float B = p0.z + p0.w*(p1.z + p1.w*(p2.z + p2.w*p3.z));
        out[pix*3+0] = R;
        out[pix*3+1] = G;
        out[pix*3+2] = B;
    }
}

extern "C" void kernel_launch(void* const* d_in, const int* in_sizes, int n_in,
                              void* d_out, int out_size, void* d_ws, size_t ws_size,
                              hipStream_t stream) {
    // d_in: 0=coords (unused by reference), 1=means, 2=quats, 3=scales, 4=opacities, 5=rgbs
    const float* means  = (const float*)d_in[1];
    const float* quats  = (const float*)d_in[2];
    const float* scales = (const float*)d_in[3];
    const float* opac   = (const float*)d_in[4];
    const float* rgbs   = (const float*)d_in[5];
    float* params = (float*)d_ws;   // NG*PG floats, 16B-aligned rows

    gs_prep<<<12, 64, 0, stream>>>(means, quats, scales, opac, rgbs, params);
    gs_composite<<<256, dim3(256,4), 0, stream>>>(params, (float*)d_out);
}

// Round 3
// 115.247 us; speedup vs baseline: 1.2103x; 1.0991x over previous
//
#include <hip/hip_runtime.h>
#include <math.h>

#define HH 256
#define WW 256
#define NG 714
#define NGP2 736           // padded row count: 8 segments x 92, all unroll-4 exact
#define SEG 92
#define NSEG 8
#define FOCALF 128.0f
#define EPS2D_F 0.3f
#define ALPHA_MIN_F (1.0f/255.0f)
#define ALPHA_MAX_F 0.999f
#define CAM_T_F 8.0f
#define LOG2E_F 1.4426950408889634f
#define PR 8               // floats per sorted row: mx,my,hA',B',hC',op,cr,cg  (cb separate)

// Kernel 1: projection + conic + stable depth rank + scatter into sorted rows.
// 3 blocks x 256 threads. conic prefolded with log2(e) so composite uses exp2.
// Rows NG..NGP2-1 zeroed (op=0 -> alpha=0 -> no contribution).
__global__ __launch_bounds__(256) void gs_prep(
    const float* __restrict__ means, const float* __restrict__ quats,
    const float* __restrict__ scales, const float* __restrict__ opacities,
    const float* __restrict__ rgbs, float* __restrict__ params,
    float* __restrict__ cbArr)
{
    __shared__ float s_tz[NGP2];
    const int lane = threadIdx.x;
    const int i = blockIdx.x * 256 + lane;

    for (int j = lane; j < NGP2; j += 256)
        s_tz[j] = (j < NG) ? (means[3*j+2] + CAM_T_F) : INFINITY;
    __syncthreads();

    if (i >= NGP2) return;
    if (i >= NG) {                      // zero the pad rows (ws is poisoned 0xAA)
        float4* row = (float4*)(params + i*PR);
        row[0] = make_float4(0.f,0.f,0.f,0.f);
        row[1] = make_float4(0.f,0.f,0.f,0.f);
        cbArr[i] = 0.f;
        return;
    }

    float m0 = means[i*3+0], m1 = means[i*3+1];
    float tz = s_tz[i];
    float qw = quats[i*4+0], qx = quats[i*4+1], qy = quats[i*4+2], qz = quats[i*4+3];
    float qn = rsqrtf(qw*qw + qx*qx + qy*qy + qz*qz);
    qw*=qn; qx*=qn; qy*=qn; qz*=qn;
    float sx = scales[i*3+0], sy = scales[i*3+1], sz = scales[i*3+2];
    float s0 = sx*sx, s1 = sy*sy, s2 = sz*sz;
    float R00 = 1.f-2.f*(qy*qy+qz*qz), R01 = 2.f*(qx*qy-qw*qz), R02 = 2.f*(qx*qz+qw*qy);
    float R10 = 2.f*(qx*qy+qw*qz),     R11 = 1.f-2.f*(qx*qx+qz*qz), R12 = 2.f*(qy*qz-qw*qx);
    float R20 = 2.f*(qx*qz-qw*qy),     R21 = 2.f*(qy*qz+qw*qx),     R22 = 1.f-2.f*(qx*qx+qy*qy);
    float S00 = R00*R00*s0 + R01*R01*s1 + R02*R02*s2;
    float S01 = R00*R10*s0 + R01*R11*s1 + R02*R12*s2;
    float S02 = R00*R20*s0 + R01*R21*s1 + R02*R22*s2;
    float S11 = R10*R10*s0 + R11*R11*s1 + R12*R12*s2;
    float S12 = R10*R20*s0 + R11*R21*s1 + R12*R22*s2;
    float S22 = R20*R20*s0 + R21*R21*s1 + R22*R22*s2;
    float inv = 1.f/tz;
    float mx = FOCALF*m0*inv + 0.5f*WW;
    float my = FOCALF*m1*inv + 0.5f*HH;
    float j0 = FOCALF*inv;
    float j2 = -FOCALF*m0*inv*inv;
    float j5 = -FOCALF*m1*inv*inv;
    float a = j0*j0*S00 + 2.f*j0*j2*S02 + j2*j2*S22 + EPS2D_F;
    float b = j0*(j0*S01 + j2*S12) + j5*(j0*S02 + j2*S22);
    float c = j0*j0*S11 + 2.f*j0*j5*S12 + j5*j5*S22 + EPS2D_F;
    float det = a*c - b*b;
    float idet = 1.f/det;
    // conic prefolded: sigma' = sigma * log2(e), alpha = op * 2^(-sigma')
    float hA = 0.5f*c*idet*LOG2E_F;
    float Bc = -b*idet*LOG2E_F;
    float hC = 0.5f*a*idet*LOG2E_F;
    float op = 1.f/(1.f+__expf(-opacities[i]));
    float cr = 1.f/(1.f+__expf(-rgbs[i*3+0]));
    float cg = 1.f/(1.f+__expf(-rgbs[i*3+1]));
    float cb = 1.f/(1.f+__expf(-rgbs[i*3+2]));

    // stable ascending rank over tz (== jnp.argsort position), float4 LDS broadcast
    const float4* t4 = (const float4*)s_tz;
    int rank = 0;
    #pragma unroll 4
    for (int jj = 0; jj < NGP2/4; ++jj) {
        float4 v = t4[jj];
        int j = 4*jj;
        rank += (v.x < tz) || (v.x == tz && (j+0) < i);
        rank += (v.y < tz) || (v.y == tz && (j+1) < i);
        rank += (v.z < tz) || (v.z == tz && (j+2) < i);
        rank += (v.w < tz) || (v.w == tz && (j+3) < i);
    }

    float4* row = (float4*)(params + rank*PR);
    row[0] = make_float4(mx, my, hA, Bc);
    row[1] = make_float4(hC, op, cr, cg);
    cbArr[rank] = cb;
}

// Kernel 2: front-to-back compositing. 2 pixels/thread (same image row ->
// dy terms shared), 8 depth segments (threadIdx.y), params via wave-uniform
// scalar loads (SMEM path), segment partials combined through LDS.
__global__ __launch_bounds__(1024) void gs_composite(
    const float* __restrict__ params, const float* __restrict__ cbArr,
    float* __restrict__ out)
{
    __shared__ float4 part[NSEG][128][2];
    const int x = threadIdx.x;                 // 0..127
    const int seg = __builtin_amdgcn_readfirstlane((int)threadIdx.y);
    const int irow = blockIdx.x;               // one image row per block
    const float py  = (float)irow + 0.5f;
    const float px0 = (float)x + 0.5f;
    const float px1 = (float)x + 128.5f;
    const int n0 = seg * SEG;

    const float4* __restrict__ p4 = (const float4*)params;
    float T0=1.f, r0=0.f, g0=0.f, b0=0.f;
    float T1=1.f, r1=0.f, g1=0.f, b1=0.f;

    #pragma unroll 4
    for (int n = n0; n < n0 + SEG; ++n) {
        float4 q0 = p4[2*n+0];                 // mx,my,hA',B'
        float4 q1 = p4[2*n+1];                 // hC',op,cr,cg
        float cbv = cbArr[n];
        float dy  = py - q0.y;
        float cyy = q1.x*dy*dy;                // hC'*dy^2  (shared)
        float bdy = q0.w*dy;                   // B'*dy     (shared)

        float dx0 = px0 - q0.x;
        float sg0 = q0.z*dx0*dx0 + bdy*dx0 + cyy;
        float al0 = fminf(q1.y*__builtin_amdgcn_exp2f(-sg0), ALPHA_MAX_F);
        al0 = (al0 < ALPHA_MIN_F) ? 0.f : al0;
        float w0 = T0*al0;
        r0 += w0*q1.z; g0 += w0*q1.w; b0 += w0*cbv; T0 -= w0;

        float dx1 = px1 - q0.x;
        float sg1 = q0.z*dx1*dx1 + bdy*dx1 + cyy;
        float al1 = fminf(q1.y*__builtin_amdgcn_exp2f(-sg1), ALPHA_MAX_F);
        al1 = (al1 < ALPHA_MIN_F) ? 0.f : al1;
        float w1 = T1*al1;
        r1 += w1*q1.z; g1 += w1*q1.w; b1 += w1*cbv; T1 -= w1;
    }

    part[seg][x][0] = make_float4(r0, g0, b0, T0);
    part[seg][x][1] = make_float4(r1, g1, b1, T1);
    __syncthreads();

    if (threadIdx.y == 0) {
        float R0=0.f,G0=0.f,B0=0.f,Ta=1.f;
        float R1=0.f,G1=0.f,B1=0.f,Tb=1.f;
        #pragma unroll
        for (int s = 0; s < NSEG; ++s) {
            float4 pa = part[s][x][0];
            float4 pb = part[s][x][1];
            R0 += Ta*pa.x; G0 += Ta*pa.y; B0 += Ta*pa.z; Ta *= pa.w;
            R1 += Tb*pb.x; G1 += Tb*pb.y; B1 += Tb*pb.z; Tb *= pb.w;
        }
        const int pixA = irow*WW + x;
        const int pixB = pixA + 128;
        out[pixA*3+0] = R0; out[pixA*3+1] = G0; out[pixA*3+2] = B0;
        out[pixB*3+0] = R1; out[pixB*3+1] = G1; out[pixB*3+2] = B1;
    }
}

extern "C" void kernel_launch(void* const* d_in, const int* in_sizes, int n_in,
                              void* d_out, int out_size, void* d_ws, size_t ws_size,
                              hipStream_t stream) {
    // d_in: 0=coords (unused by reference), 1=means, 2=quats, 3=scales, 4=opacities, 5=rgbs
    const float* means  = (const float*)d_in[1];
    const float* quats  = (const float*)d_in[2];
    const float* scales = (const float*)d_in[3];
    const float* opac   = (const float*)d_in[4];
    const float* rgbs   = (const float*)d_in[5];
    float* params = (float*)d_ws;                 // NGP2*PR floats
    float* cbArr  = params + NGP2*PR;             // NGP2 floats

    gs_prep<<<3, 256, 0, stream>>>(means, quats, scales, opac, rgbs, params, cbArr);
    gs_composite<<<HH, dim3(128, NSEG), 0, stream>>>(params, cbArr, (float*)d_out);
}

// Round 4
// 112.044 us; speedup vs baseline: 1.2449x; 1.0286x over previous
//
#include <hip/hip_runtime.h>
#include <math.h>

#define HH 256
#define WW 256
#define NG 714
#define NGP 736            // 16 segments x 46 rows
#define SEG 46
#define NSEG 16
#define FOCALF 128.0f
#define EPS2D_F 0.3f
#define ALPHA_MIN_F (1.0f/255.0f)
#define CAM_T_F 8.0f
#define LOG2E_F 1.4426950408889634f
#define PR 12              // floats/row: [mx,my,A2n,B2n][C2n,op,cr,cg][cb,e,thr,0]

// Kernel 1: projection + conic + stable depth rank + scatter into sorted rows.
// Conic stored NEGATED and prefolded with log2(e): sg = A2n*dx^2+B2n*dx*dy+C2n*dy^2
// equals -sigma*log2e, so alpha = op * exp2(sg). e/thr are the cull params:
// skip gaussian for a wave iff e*dymin^2 > thr (=> alpha < 1/255 for every dx).
__global__ __launch_bounds__(256) void gs_prep(
    const float* __restrict__ means, const float* __restrict__ quats,
    const float* __restrict__ scales, const float* __restrict__ opacities,
    const float* __restrict__ rgbs, float* __restrict__ params)
{
    __shared__ float s_tz[NGP];
    const int lane = threadIdx.x;
    const int i = blockIdx.x * 256 + lane;

    for (int j = lane; j < NGP; j += 256)
        s_tz[j] = (j < NG) ? (means[3*j+2] + CAM_T_F) : INFINITY;
    __syncthreads();

    if (i >= NGP) return;
    if (i >= NG) {                      // pad rows: culled always (e=0 > thr=-1)
        float4* row = (float4*)(params + i*PR);
        row[0] = make_float4(0.f,0.f,0.f,0.f);
        row[1] = make_float4(0.f,0.f,0.f,0.f);
        row[2] = make_float4(0.f,0.f,-1.f,0.f);
        return;
    }

    float m0 = means[i*3+0], m1 = means[i*3+1];
    float tz = s_tz[i];
    float qw = quats[i*4+0], qx = quats[i*4+1], qy = quats[i*4+2], qz = quats[i*4+3];
    float qn = rsqrtf(qw*qw + qx*qx + qy*qy + qz*qz);
    qw*=qn; qx*=qn; qy*=qn; qz*=qn;
    float sx = scales[i*3+0], sy = scales[i*3+1], sz = scales[i*3+2];
    float s0 = sx*sx, s1 = sy*sy, s2 = sz*sz;
    float R00 = 1.f-2.f*(qy*qy+qz*qz), R01 = 2.f*(qx*qy-qw*qz), R02 = 2.f*(qx*qz+qw*qy);
    float R10 = 2.f*(qx*qy+qw*qz),     R11 = 1.f-2.f*(qx*qx+qz*qz), R12 = 2.f*(qy*qz-qw*qx);
    float R20 = 2.f*(qx*qz-qw*qy),     R21 = 2.f*(qy*qz+qw*qx),     R22 = 1.f-2.f*(qx*qx+qy*qy);
    float S00 = R00*R00*s0 + R01*R01*s1 + R02*R02*s2;
    float S01 = R00*R10*s0 + R01*R11*s1 + R02*R12*s2;
    float S02 = R00*R20*s0 + R01*R21*s1 + R02*R22*s2;
    float S11 = R10*R10*s0 + R11*R11*s1 + R12*R12*s2;
    float S12 = R10*R20*s0 + R11*R21*s1 + R12*R22*s2;
    float S22 = R20*R20*s0 + R21*R21*s1 + R22*R22*s2;
    float inv = 1.f/tz;
    float mx = FOCALF*m0*inv + 0.5f*WW;
    float my = FOCALF*m1*inv + 0.5f*HH;
    float j0 = FOCALF*inv;
    float j2 = -FOCALF*m0*inv*inv;
    float j5 = -FOCALF*m1*inv*inv;
    float a = j0*j0*S00 + 2.f*j0*j2*S02 + j2*j2*S22 + EPS2D_F;
    float b = j0*(j0*S01 + j2*S12) + j5*(j0*S02 + j2*S22);
    float c = j0*j0*S11 + 2.f*j0*j5*S12 + j5*j5*S22 + EPS2D_F;
    float det = a*c - b*b;
    float idet = 1.f/det;
    float hA = 0.5f*c*idet*LOG2E_F;      // positive conic terms (log2-scaled)
    float Bc = -b*idet*LOG2E_F;
    float hC = 0.5f*a*idet*LOG2E_F;
    float e  = hC - Bc*Bc/(4.f*hA);      // >= 0 (PSD): min over dx of sigma' = e*dy^2
    float op = 1.f/(1.f+__expf(-opacities[i]));
    float thr = log2f(255.f*op);         // cull iff e*dy^2 > thr
    float cr = 1.f/(1.f+__expf(-rgbs[i*3+0]));
    float cg = 1.f/(1.f+__expf(-rgbs[i*3+1]));
    float cb = 1.f/(1.f+__expf(-rgbs[i*3+2]));

    const float4* t4 = (const float4*)s_tz;
    int rank = 0;
    #pragma unroll 4
    for (int jj = 0; jj < NGP/4; ++jj) {
        float4 v = t4[jj];
        int j = 4*jj;
        rank += (v.x < tz) || (v.x == tz && (j+0) < i);
        rank += (v.y < tz) || (v.y == tz && (j+1) < i);
        rank += (v.z < tz) || (v.z == tz && (j+2) < i);
        rank += (v.w < tz) || (v.w == tz && (j+3) < i);
    }

    float4* row = (float4*)(params + rank*PR);
    row[0] = make_float4(mx, my, -hA, -Bc);   // negated for exp2(sg) directly
    row[1] = make_float4(-hC, op, cr, cg);
    row[2] = make_float4(cb, e, thr, 0.f);
}

// Kernel 2: compositing. 4 px/thread spread vertically (rows yg, yg+64,
// yg+128, yg+192; same x -> dx terms shared, perfect load balance).
// 16 depth segments (threadIdx.y), params via wave-uniform s_load path,
// per-gaussian conservative y-cull with a scalar branch.
// NOTE: fmin(alpha, 0.999) dropped — op = sigmoid(1) = 0.731 < 0.999 always.
__global__ __launch_bounds__(1024, 1) void gs_composite(
    const float* __restrict__ params, float* __restrict__ out)
{
    __shared__ float4 part[4][NSEG][64];    // [pxrow k][seg][tx] — lane-contiguous
    const int tx = threadIdx.x;             // 0..63
    const int seg = __builtin_amdgcn_readfirstlane((int)threadIdx.y);
    const int bid = blockIdx.x;             // 256 blocks: 4 x-tiles x 64 y-groups
    const int xt = bid & 3;
    const int yg = bid >> 2;
    const float px  = (float)(xt*64 + tx) + 0.5f;
    const float py0 = (float)yg + 0.5f;
    const int n0 = seg * SEG;

    const float4* __restrict__ p4 = (const float4*)params;
    float T0=1.f,r0=0.f,g0=0.f,b0=0.f;
    float T1=1.f,r1=0.f,g1=0.f,b1=0.f;
    float T2=1.f,r2=0.f,g2=0.f,b2=0.f;
    float T3=1.f,r3=0.f,g3=0.f,b3=0.f;

    for (int n = n0; n < n0 + SEG; ++n) {
        float4 q0 = p4[3*n+0];              // mx,my,A2n,B2n
        float4 q1 = p4[3*n+1];              // C2n,op,cr,cg
        float4 q2 = p4[3*n+2];              // cb,e,thr,0
        float dy0 = py0 - q0.y;
        float dy1 = dy0 + 64.f, dy2 = dy0 + 128.f, dy3 = dy0 + 192.f;
        float dmin = fminf(fminf(fabsf(dy0), fabsf(dy1)),
                           fminf(fabsf(dy2), fabsf(dy3)));
        // wave-uniform cull: alpha < 1/255 for every dx at all 4 rows
        if (__builtin_amdgcn_readfirstlane((int)(q2.y*dmin*dmin > q2.z)))
            continue;
        float dx  = px - q0.x;
        float axx = q0.z*dx*dx;             // A2n*dx^2  (shared across 4 rows)
        float bdx = q0.w*dx;                // B2n*dx

        float sg0 = fmaf(bdx, dy0, fmaf(q1.x*dy0, dy0, axx));
        float al0 = q1.y * __builtin_amdgcn_exp2f(sg0);
        al0 = (al0 < ALPHA_MIN_F) ? 0.f : al0;
        float w0 = T0*al0; r0 += w0*q1.z; g0 += w0*q1.w; b0 += w0*q2.x; T0 -= w0;

        float sg1 = fmaf(bdx, dy1, fmaf(q1.x*dy1, dy1, axx));
        float al1 = q1.y * __builtin_amdgcn_exp2f(sg1);
        al1 = (al1 < ALPHA_MIN_F) ? 0.f : al1;
        float w1 = T1*al1; r1 += w1*q1.z; g1 += w1*q1.w; b1 += w1*q2.x; T1 -= w1;

        float sg2 = fmaf(bdx, dy2, fmaf(q1.x*dy2, dy2, axx));
        float al2 = q1.y * __builtin_amdgcn_exp2f(sg2);
        al2 = (al2 < ALPHA_MIN_F) ? 0.f : al2;
        float w2 = T2*al2; r2 += w2*q1.z; g2 += w2*q1.w; b2 += w2*q2.x; T2 -= w2;

        float sg3 = fmaf(bdx, dy3, fmaf(q1.x*dy3, dy3, axx));
        float al3 = q1.y * __builtin_amdgcn_exp2f(sg3);
        al3 = (al3 < ALPHA_MIN_F) ? 0.f : al3;
        float w3 = T3*al3; r3 += w3*q1.z; g3 += w3*q1.w; b3 += w3*q2.x; T3 -= w3;
    }

    part[0][seg][tx] = make_float4(r0,g0,b0,T0);
    part[1][seg][tx] = make_float4(r1,g1,b1,T1);
    part[2][seg][tx] = make_float4(r2,g2,b2,T2);
    part[3][seg][tx] = make_float4(r3,g3,b3,T3);
    __syncthreads();

    if (threadIdx.y < 4) {                  // 4 waves, one pixel-row each
        const int k = threadIdx.y;
        float R=0.f,G=0.f,B=0.f,T=1.f;
        #pragma unroll
        for (int s = 0; s < NSEG; ++s) {
            float4 v = part[k][s][tx];
            R += T*v.x; G += T*v.y; B += T*v.z; T *= v.w;
        }
        const int y = yg + (k<<6);
        const int pix = y*WW + xt*64 + tx;
        out[pix*3+0] = R; out[pix*3+1] = G; out[pix*3+2] = B;
    }
}

extern "C" void kernel_launch(void* const* d_in, const int* in_sizes, int n_in,
                              void* d_out, int out_size, void* d_ws, size_t ws_size,
                              hipStream_t stream) {
    // d_in: 0=coords (unused by reference), 1=means, 2=quats, 3=scales, 4=opacities, 5=rgbs
    const float* means  = (const float*)d_in[1];
    const float* quats  = (const float*)d_in[2];
    const float* scales = (const float*)d_in[3];
    const float* opac   = (const float*)d_in[4];
    const float* rgbs   = (const float*)d_in[5];
    float* params = (float*)d_ws;                 // NGP*PR floats

    gs_prep<<<3, 256, 0, stream>>>(means, quats, scales, opac, rgbs, params);
    gs_composite<<<256, dim3(64, NSEG), 0, stream>>>(params, (float*)d_out);
}

// Round 5
// 108.336 us; speedup vs baseline: 1.2876x; 1.0342x over previous
//
#include <hip/hip_runtime.h>
#include <math.h>

#define HH 256
#define WW 256
#define NG 714
#define NGP 736            // 16 segments x 46 rows
#define NROWS 738          // +2 pad rows for distance-2 prefetch
#define SEG 46
#define NSEG 16
#define FOCALF 128.0f
#define EPS2D_F 0.3f
#define ALPHA_MIN_F (1.0f/255.0f)
#define CAM_T_F 8.0f
#define LOG2E_F 1.4426950408889634f
#define PR 12              // floats/row: [mx,my,A2n,B2n][C2n,op,cr,cg][cb,e,f,thr]
#define T_EPS 0.003f       // wave early-out when all lanes' T < T_EPS (err <= T_EPS)

// Kernel 1: projection + conic + stable depth rank + scatter into sorted rows.
// Conic stored NEGATED, prefolded with log2(e): sg = A2n*dx^2+B2n*dx*dy+C2n*dy^2
// = -sigma*log2e, alpha = op*exp2(sg). Cull params: e = C-B^2/4A, f = A-B^2/4C
// (positive-conic terms, both >=0); skip gaussian for a wave iff
// max(e*dymin^2, f*dxmin^2) > thr = log2(255*op)  (=> alpha < 1/255 on the box).
__global__ __launch_bounds__(256) void gs_prep(
    const float* __restrict__ means, const float* __restrict__ quats,
    const float* __restrict__ scales, const float* __restrict__ opacities,
    const float* __restrict__ rgbs, float* __restrict__ params)
{
    __shared__ float s_tz[NGP];
    const int lane = threadIdx.x;
    const int i = blockIdx.x * 256 + lane;

    for (int j = lane; j < NGP; j += 256)
        s_tz[j] = (j < NG) ? (means[3*j+2] + CAM_T_F) : INFINITY;
    __syncthreads();

    if (i >= NROWS) return;
    if (i >= NG) {                      // pad rows: always culled (0 > thr=-1)
        float4* row = (float4*)(params + i*PR);
        row[0] = make_float4(0.f,0.f,0.f,0.f);
        row[1] = make_float4(0.f,0.f,0.f,0.f);
        row[2] = make_float4(0.f,0.f,0.f,-1.f);
        return;
    }

    float m0 = means[i*3+0], m1 = means[i*3+1];
    float tz = s_tz[i];
    float qw = quats[i*4+0], qx = quats[i*4+1], qy = quats[i*4+2], qz = quats[i*4+3];
    float qn = rsqrtf(qw*qw + qx*qx + qy*qy + qz*qz);
    qw*=qn; qx*=qn; qy*=qn; qz*=qn;
    float sx = scales[i*3+0], sy = scales[i*3+1], sz = scales[i*3+2];
    float s0 = sx*sx, s1 = sy*sy, s2 = sz*sz;
    float R00 = 1.f-2.f*(qy*qy+qz*qz), R01 = 2.f*(qx*qy-qw*qz), R02 = 2.f*(qx*qz+qw*qy);
    float R10 = 2.f*(qx*qy+qw*qz),     R11 = 1.f-2.f*(qx*qx+qz*qz), R12 = 2.f*(qy*qz-qw*qx);
    float R20 = 2.f*(qx*qz-qw*qy),     R21 = 2.f*(qy*qz+qw*qx),     R22 = 1.f-2.f*(qx*qx+qy*qy);
    float S00 = R00*R00*s0 + R01*R01*s1 + R02*R02*s2;
    float S01 = R00*R10*s0 + R01*R11*s1 + R02*R12*s2;
    float S02 = R00*R20*s0 + R01*R21*s1 + R02*R22*s2;
    float S11 = R10*R10*s0 + R11*R11*s1 + R12*R12*s2;
    float S12 = R10*R20*s0 + R11*R21*s1 + R12*R22*s2;
    float S22 = R20*R20*s0 + R21*R21*s1 + R22*R22*s2;
    float inv = 1.f/tz;
    float mx = FOCALF*m0*inv + 0.5f*WW;
    float my = FOCALF*m1*inv + 0.5f*HH;
    float j0 = FOCALF*inv;
    float j2 = -FOCALF*m0*inv*inv;
    float j5 = -FOCALF*m1*inv*inv;
    float a = j0*j0*S00 + 2.f*j0*j2*S02 + j2*j2*S22 + EPS2D_F;
    float b = j0*(j0*S01 + j2*S12) + j5*(j0*S02 + j2*S22);
    float c = j0*j0*S11 + 2.f*j0*j5*S12 + j5*j5*S22 + EPS2D_F;
    float det = a*c - b*b;
    float idet = 1.f/det;
    float hA = 0.5f*c*idet*LOG2E_F;      // positive conic terms (log2-scaled)
    float Bc = -b*idet*LOG2E_F;
    float hC = 0.5f*a*idet*LOG2E_F;
    float e  = hC - Bc*Bc/(4.f*hA);      // min over dx of sigma' = e*dy^2
    float f  = hA - Bc*Bc/(4.f*hC);      // min over dy of sigma' = f*dx^2
    float op = 1.f/(1.f+__expf(-opacities[i]));
    float thr = log2f(255.f*op);         // cull iff max bound > thr
    float cr = 1.f/(1.f+__expf(-rgbs[i*3+0]));
    float cg = 1.f/(1.f+__expf(-rgbs[i*3+1]));
    float cb = 1.f/(1.f+__expf(-rgbs[i*3+2]));

    const float4* t4 = (const float4*)s_tz;
    int rank = 0;
    #pragma unroll 4
    for (int jj = 0; jj < NGP/4; ++jj) {
        float4 v = t4[jj];
        int j = 4*jj;
        rank += (v.x < tz) || (v.x == tz && (j+0) < i);
        rank += (v.y < tz) || (v.y == tz && (j+1) < i);
        rank += (v.z < tz) || (v.z == tz && (j+2) < i);
        rank += (v.w < tz) || (v.w == tz && (j+3) < i);
    }

    float4* row = (float4*)(params + rank*PR);
    row[0] = make_float4(mx, my, -hA, -Bc);   // negated: alpha = op*exp2(sg)
    row[1] = make_float4(-hC, op, cr, cg);
    row[2] = make_float4(cb, e, f, thr);
}

// Kernel 2: compositing. Thread = 4 CONTIGUOUS rows (y..y+3) at one x ->
// wave cull box is 64x4 px (tight). 16 depth segments (threadIdx.y), params
// via wave-uniform s_load with distance-2 register prefetch. Wave-wide early
// termination when all lanes saturate (T < T_EPS; bounded error < T_EPS).
__global__ __launch_bounds__(1024, 1) void gs_composite(
    const float* __restrict__ params, float* __restrict__ out)
{
    __shared__ float4 part[4][NSEG][64];    // [row k][seg][tx]
    const int tx = threadIdx.x;             // 0..63
    const int seg = __builtin_amdgcn_readfirstlane((int)threadIdx.y);
    const int xt = blockIdx.x & 3;          // x-tile (64 px)
    const int yg = blockIdx.x >> 2;         // y-group (4 contiguous rows)
    const float px   = (float)(xt*64 + tx) + 0.5f;
    const float xc   = (float)(xt*64) + 32.0f;   // box center x (half-span 31.5)
    const float yb   = (float)(yg*4) + 0.5f;     // row-0 center
    const float ycen = (float)(yg*4) + 2.0f;     // box center y (half-span 1.5)
    const int n0 = seg * SEG;

    const float4* p = ((const float4*)params) + 3*n0;
    float4 a0=p[0], a1=p[1], a2=p[2];
    float4 b0=p[3], b1=p[4], b2=p[5];

    float T0=1.f,r0=0.f,g0=0.f,bl0=0.f;
    float T1=1.f,r1=0.f,g1=0.f,bl1=0.f;
    float T2=1.f,r2=0.f,g2=0.f,bl2=0.f;
    float T3=1.f,r3=0.f,g3=0.f,bl3=0.f;

    for (int n = 0; n < SEG; ++n) {
        float4 c0=p[6], c1=p[7], c2=p[8]; p += 3;   // prefetch n+2 (pad rows cover tail)
        float dyc = fabsf(ycen - a0.y);
        float dymin = fmaxf(dyc - 1.5f, 0.f);
        float dxc = fabsf(xc - a0.x);
        float dxmin = fmaxf(dxc - 31.5f, 0.f);
        float m = fmaxf(a2.y*dymin*dymin, a2.z*dxmin*dxmin);
        if (!(m > a2.w)) {                          // wave-uniform branch
            float dy0 = yb - a0.y;
            float dy1 = dy0 + 1.f, dy2 = dy0 + 2.f, dy3 = dy0 + 3.f;
            float dx  = px - a0.x;
            float axx = a0.z*dx*dx;
            float bdx = a0.w*dx;

            float sg0 = fmaf(bdx, dy0, fmaf(a1.x*dy0, dy0, axx));
            float al0 = a1.y * __builtin_amdgcn_exp2f(sg0);
            al0 = (al0 < ALPHA_MIN_F) ? 0.f : al0;
            float w0 = T0*al0; r0 += w0*a1.z; g0 += w0*a1.w; bl0 += w0*a2.x; T0 -= w0;

            float sg1 = fmaf(bdx, dy1, fmaf(a1.x*dy1, dy1, axx));
            float al1 = a1.y * __builtin_amdgcn_exp2f(sg1);
            al1 = (al1 < ALPHA_MIN_F) ? 0.f : al1;
            float w1 = T1*al1; r1 += w1*a1.z; g1 += w1*a1.w; bl1 += w1*a2.x; T1 -= w1;

            float sg2 = fmaf(bdx, dy2, fmaf(a1.x*dy2, dy2, axx));
            float al2 = a1.y * __builtin_amdgcn_exp2f(sg2);
            al2 = (al2 < ALPHA_MIN_F) ? 0.f : al2;
            float w2 = T2*al2; r2 += w2*a1.z; g2 += w2*a1.w; bl2 += w2*a2.x; T2 -= w2;

            float sg3 = fmaf(bdx, dy3, fmaf(a1.x*dy3, dy3, axx));
            float al3 = a1.y * __builtin_amdgcn_exp2f(sg3);
            al3 = (al3 < ALPHA_MIN_F) ? 0.f : al3;
            float w3 = T3*al3; r3 += w3*a1.z; g3 += w3*a1.w; bl3 += w3*a2.x; T3 -= w3;

            // wave-wide early termination: remaining contribution <= T < T_EPS
            float tmax = fmaxf(fmaxf(T0,T1), fmaxf(T2,T3));
            if (__ballot(tmax > T_EPS) == 0ull) break;
        }
        a0=b0; a1=b1; a2=b2;
        b0=c0; b1=c1; b2=c2;
    }

    part[0][seg][tx] = make_float4(r0,g0,bl0,T0);
    part[1][seg][tx] = make_float4(r1,g1,bl1,T1);
    part[2][seg][tx] = make_float4(r2,g2,bl2,T2);
    part[3][seg][tx] = make_float4(r3,g3,bl3,T3);
    __syncthreads();

    if (threadIdx.y < 4) {                  // 4 waves, one pixel-row each
        const int k = threadIdx.y;
        float R=0.f,G=0.f,B=0.f,T=1.f;
        #pragma unroll
        for (int s = 0; s < NSEG; ++s) {
            float4 v = part[k][s][tx];
            R += T*v.x; G += T*v.y; B += T*v.z; T *= v.w;
        }
        const int y = yg*4 + k;
        const int pix = y*WW + xt*64 + tx;
        out[pix*3+0] = R; out[pix*3+1] = G; out[pix*3+2] = B;
    }
}

extern "C" void kernel_launch(void* const* d_in, const int* in_sizes, int n_in,
                              void* d_out, int out_size, void* d_ws, size_t ws_size,
                              hipStream_t stream) {
    // d_in: 0=coords (unused by reference), 1=means, 2=quats, 3=scales, 4=opacities, 5=rgbs
    const float* means  = (const float*)d_in[1];
    const float* quats  = (const float*)d_in[2];
    const float* scales = (const float*)d_in[3];
    const float* opac   = (const float*)d_in[4];
    const float* rgbs   = (const float*)d_in[5];
    float* params = (float*)d_ws;                 // NROWS*PR floats

    gs_prep<<<3, 256, 0, stream>>>(means, quats, scales, opac, rgbs, params);
    gs_composite<<<256, dim3(64, NSEG), 0, stream>>>(params, (float*)d_out);
}